// Round 6
// baseline (864.043 us; speedup 1.0000x reference)
//
#include <hip/hip_runtime.h>
#include <math.h>
#include <cstddef>

#define NN 100000
#define NE 1600000
#define CH 256
#define OC 40

typedef __attribute__((ext_vector_type(8))) short bf16x8;
typedef __attribute__((ext_vector_type(4))) float f32x4;

static __device__ __forceinline__ unsigned short f2bf(float f) {
    unsigned int u = __float_as_uint(f);
    unsigned int r = (u + 0x7FFFu + ((u >> 16) & 1u)) >> 16;
    return (unsigned short)r;
}
static __device__ __forceinline__ float bflo(unsigned int u) {
    return __uint_as_float(u << 16);
}
static __device__ __forceinline__ float bfhi(unsigned int u) {
    return __uint_as_float(u & 0xFFFF0000u);
}
static __device__ __forceinline__ uint4 ld_f32x8_to_bf8(const float* p) {
    float4 a = *reinterpret_cast<const float4*>(p);
    float4 b = *reinterpret_cast<const float4*>(p + 4);
    uint4 r;
    r.x = f2bf(a.x) | ((unsigned)f2bf(a.y) << 16);
    r.y = f2bf(a.z) | ((unsigned)f2bf(a.w) << 16);
    r.z = f2bf(b.x) | ((unsigned)f2bf(b.y) << 16);
    r.w = f2bf(b.z) | ((unsigned)f2bf(b.w) << 16);
    return r;
}

// ---------------- graph build ----------------

__global__ void hist_kernel(const int* __restrict__ dst, int* __restrict__ deg, int E) {
    int i = blockIdx.x * blockDim.x + threadIdx.x;
    int st = gridDim.x * blockDim.x;
    for (; i < E; i += st) atomicAdd(&deg[dst[i]], 1);
}

__global__ void dinv_kernel(const int* __restrict__ deg, float* __restrict__ dinv, int n) {
    int i = blockIdx.x * blockDim.x + threadIdx.x;
    if (i < n) dinv[i] = rsqrtf((float)deg[i] + 1.0f);
}

// ---- hierarchical scan: row_ptr = exclusive_scan(deg+1), row_ptr[n] = total ----
__global__ __launch_bounds__(256) void scan1_kernel(const int* __restrict__ deg,
        int* __restrict__ row_ptr, int* __restrict__ bsum, int n) {
    __shared__ int s[256];
    int t = threadIdx.x;
    int i = blockIdx.x * 256 + t;
    int v = (i < n) ? deg[i] + 1 : 0;
    s[t] = v;
    __syncthreads();
    #pragma unroll
    for (int off = 1; off < 256; off <<= 1) {
        int u = (t >= off) ? s[t - off] : 0;
        __syncthreads();
        s[t] += u;
        __syncthreads();
    }
    if (i < n) row_ptr[i] = s[t] - v;
    if (t == 255) bsum[blockIdx.x] = s[255];
}

__global__ __launch_bounds__(512) void scan2_kernel(const int* __restrict__ bsum,
        int* __restrict__ boff, int* __restrict__ row_ptr, int nb, int n) {
    __shared__ int s[512];
    int t = threadIdx.x;
    int v = (t < nb) ? bsum[t] : 0;
    s[t] = v;
    __syncthreads();
    #pragma unroll
    for (int off = 1; off < 512; off <<= 1) {
        int u = (t >= off) ? s[t - off] : 0;
        __syncthreads();
        s[t] += u;
        __syncthreads();
    }
    if (t < nb) boff[t] = s[t] - v;
    if (t == nb - 1) row_ptr[n] = s[t];
}

__global__ __launch_bounds__(256) void scan3_kernel(int* __restrict__ row_ptr,
        const int* __restrict__ boff, int n) {
    int i = blockIdx.x * 256 + threadIdx.x;
    if (i < n) row_ptr[i] += boff[i >> 8];
}

__global__ __launch_bounds__(256) void cpy_kernel(const int* __restrict__ rp,
        int* __restrict__ cursor, int n) {
    int i = blockIdx.x * 256 + threadIdx.x;
    if (i < n) cursor[i] = rp[i];
}

// scatter src ids only; norm recomputed in agg from dinv. Self-loop at row end.
__global__ void fill_kernel(const int* __restrict__ src, const int* __restrict__ dst,
                            const int* __restrict__ row_ptr, int* __restrict__ cursor,
                            int* __restrict__ csr_src, int E, int n) {
    int i = blockIdx.x * blockDim.x + threadIdx.x;
    int st = gridDim.x * blockDim.x;
    int total = E + n;
    for (; i < total; i += st) {
        if (i < E) {
            int s = src[i], d = dst[i];
            int pos = atomicAdd(&cursor[d], 1);
            csr_src[pos] = s;
        } else {
            int v = i - E;
            csr_src[row_ptr[v + 1] - 1] = v;
        }
    }
}

// ---------------- prep ----------------

__global__ void wtrans_kernel(const float* __restrict__ W, unsigned short* __restrict__ Wt) {
    __shared__ float tile[16][17];
    int k = blockIdx.y * 16 + threadIdx.y;
    int n = blockIdx.x * 16 + threadIdx.x;
    tile[threadIdx.y][threadIdx.x] = W[(size_t)k * 256 + n];
    __syncthreads();
    int on = blockIdx.x * 16 + threadIdx.y;
    int ok = blockIdx.y * 16 + threadIdx.x;
    Wt[(size_t)on * 256 + ok] = f2bf(tile[threadIdx.x][threadIdx.y]);
}

// ---------------- layer-1 GEMM: C[M x 256] = bf16(A_f32[M x 256]) @ Wt^T ----------------
__global__ __launch_bounds__(256) void gemm_l1_kernel(
        const float* __restrict__ A, const unsigned short* __restrict__ Wt,
        unsigned short* __restrict__ C, int M) {
    __shared__ __align__(16) unsigned short As[128 * 40];
    __shared__ __align__(16) unsigned short Bs[128 * 40];
    const int t = threadIdx.x;
    const int l = t & 63;
    const int w = t >> 6;
    const int wr = w >> 1, wc = w & 1;
    const int row0 = blockIdx.x * 128;
    const int col0 = blockIdx.y * 128;

    f32x4 acc[4][4];
    #pragma unroll
    for (int m = 0; m < 4; m++)
        #pragma unroll
        for (int n = 0; n < 4; n++) acc[m][n] = (f32x4){0.f, 0.f, 0.f, 0.f};

    const int sr = t >> 2;
    const int sc = (t & 3) * 8;
    const int rl = l & 15;
    const int kb = (l >> 4) * 8;

    uint4 va[2], ub[2];
    #pragma unroll
    for (int p = 0; p < 2; p++) {
        int r = sr + p * 64;
        int gr = row0 + r;
        va[p] = (gr < M) ? ld_f32x8_to_bf8(A + (size_t)gr * 256 + sc)
                         : make_uint4(0u, 0u, 0u, 0u);
        ub[p] = *reinterpret_cast<const uint4*>(Wt + (size_t)(col0 + r) * 256 + sc);
    }

    for (int k0 = 0; k0 < 256; k0 += 32) {
        #pragma unroll
        for (int p = 0; p < 2; p++) {
            int r = sr + p * 64;
            *reinterpret_cast<uint4*>(&As[r * 40 + sc]) = va[p];
            *reinterpret_cast<uint4*>(&Bs[r * 40 + sc]) = ub[p];
        }
        __syncthreads();
        if (k0 + 32 < 256) {
            #pragma unroll
            for (int p = 0; p < 2; p++) {
                int r = sr + p * 64;
                int gr = row0 + r;
                va[p] = (gr < M) ? ld_f32x8_to_bf8(A + (size_t)gr * 256 + k0 + 32 + sc)
                                 : make_uint4(0u, 0u, 0u, 0u);
                ub[p] = *reinterpret_cast<const uint4*>(Wt + (size_t)(col0 + r) * 256 + k0 + 32 + sc);
            }
        }
        bf16x8 af[4], bfr[4];
        #pragma unroll
        for (int m = 0; m < 4; m++)
            af[m] = *reinterpret_cast<const bf16x8*>(&As[(wr * 64 + m * 16 + rl) * 40 + kb]);
        #pragma unroll
        for (int n = 0; n < 4; n++)
            bfr[n] = *reinterpret_cast<const bf16x8*>(&Bs[(wc * 64 + n * 16 + rl) * 40 + kb]);
        #pragma unroll
        for (int m = 0; m < 4; m++)
            #pragma unroll
            for (int n = 0; n < 4; n++)
                acc[m][n] = __builtin_amdgcn_mfma_f32_16x16x32_bf16(af[m], bfr[n], acc[m][n], 0, 0, 0);
        __syncthreads();
    }
    const int rh = l >> 4;
    #pragma unroll
    for (int m = 0; m < 4; m++) {
        #pragma unroll
        for (int n = 0; n < 4; n++) {
            #pragma unroll
            for (int j = 0; j < 4; j++) {
                int gr = row0 + wr * 64 + m * 16 + rh * 4 + j;
                int gc = col0 + wc * 64 + n * 16 + rl;
                if (gr < M) C[(size_t)gr * 256 + gc] = f2bf(acc[m][n][j]);
            }
        }
    }
}

// ---------------- bf16 MFMA GEMM (bf16 A) ----------------
__global__ __launch_bounds__(256) void gemm_bf16_kernel(
        const unsigned short* __restrict__ A, const unsigned short* __restrict__ Wt,
        unsigned short* __restrict__ C, int M) {
    __shared__ __align__(16) unsigned short As[128 * 40];
    __shared__ __align__(16) unsigned short Bs[128 * 40];
    const int t = threadIdx.x;
    const int l = t & 63;
    const int w = t >> 6;
    const int wr = w >> 1, wc = w & 1;
    const int row0 = blockIdx.x * 128;
    const int col0 = blockIdx.y * 128;

    f32x4 acc[4][4];
    #pragma unroll
    for (int m = 0; m < 4; m++)
        #pragma unroll
        for (int n = 0; n < 4; n++) acc[m][n] = (f32x4){0.f, 0.f, 0.f, 0.f};

    const int sr = t >> 2;
    const int sc = (t & 3) * 8;
    const int rl = l & 15;
    const int kb = (l >> 4) * 8;

    uint4 va[2], ub[2];
    #pragma unroll
    for (int p = 0; p < 2; p++) {
        int r = sr + p * 64;
        int gr = row0 + r;
        va[p] = (gr < M) ? *reinterpret_cast<const uint4*>(A + (size_t)gr * 256 + sc)
                         : make_uint4(0u, 0u, 0u, 0u);
        ub[p] = *reinterpret_cast<const uint4*>(Wt + (size_t)(col0 + r) * 256 + sc);
    }

    for (int k0 = 0; k0 < 256; k0 += 32) {
        #pragma unroll
        for (int p = 0; p < 2; p++) {
            int r = sr + p * 64;
            *reinterpret_cast<uint4*>(&As[r * 40 + sc]) = va[p];
            *reinterpret_cast<uint4*>(&Bs[r * 40 + sc]) = ub[p];
        }
        __syncthreads();
        if (k0 + 32 < 256) {
            #pragma unroll
            for (int p = 0; p < 2; p++) {
                int r = sr + p * 64;
                int gr = row0 + r;
                va[p] = (gr < M) ? *reinterpret_cast<const uint4*>(A + (size_t)gr * 256 + k0 + 32 + sc)
                                 : make_uint4(0u, 0u, 0u, 0u);
                ub[p] = *reinterpret_cast<const uint4*>(Wt + (size_t)(col0 + r) * 256 + k0 + 32 + sc);
            }
        }
        bf16x8 af[4], bfr[4];
        #pragma unroll
        for (int m = 0; m < 4; m++)
            af[m] = *reinterpret_cast<const bf16x8*>(&As[(wr * 64 + m * 16 + rl) * 40 + kb]);
        #pragma unroll
        for (int n = 0; n < 4; n++)
            bfr[n] = *reinterpret_cast<const bf16x8*>(&Bs[(wc * 64 + n * 16 + rl) * 40 + kb]);
        #pragma unroll
        for (int m = 0; m < 4; m++)
            #pragma unroll
            for (int n = 0; n < 4; n++)
                acc[m][n] = __builtin_amdgcn_mfma_f32_16x16x32_bf16(af[m], bfr[n], acc[m][n], 0, 0, 0);
        __syncthreads();
    }
    const int rh = l >> 4;
    #pragma unroll
    for (int m = 0; m < 4; m++) {
        #pragma unroll
        for (int n = 0; n < 4; n++) {
            #pragma unroll
            for (int j = 0; j < 4; j++) {
                int gr = row0 + wr * 64 + m * 16 + rh * 4 + j;
                int gc = col0 + wc * 64 + n * 16 + rl;
                if (gr < M) C[(size_t)gr * 256 + gc] = f2bf(acc[m][n][j]);
            }
        }
    }
}

// ---------------- GEMM: T3[M x 40] = Hb(bf16) @ W3(f32) ----------------
__global__ __launch_bounds__(256) void gemm40_kernel(const unsigned short* __restrict__ A,
                                                     const float* __restrict__ W,
                                                     float* __restrict__ C, int M) {
    __shared__ float Hs[128][65];
    __shared__ float Ws[64][40];
    const int t = threadIdx.x;
    const int tr = t & 127;
    const int tg = t >> 7;
    const int row0 = blockIdx.x * 128;
    float acc[20];
    #pragma unroll
    for (int j = 0; j < 20; j++) acc[j] = 0.f;

    const int hr = t >> 4;
    const int hc = (t & 15) << 2;

    for (int k0 = 0; k0 < 256; k0 += 64) {
        #pragma unroll
        for (int p = 0; p < 8; p++) {
            int r = hr + p * 16;
            int gr = row0 + r;
            uint2 u = make_uint2(0u, 0u);
            if (gr < M) u = *reinterpret_cast<const uint2*>(A + (size_t)gr * 256 + k0 + hc);
            Hs[r][hc] = bflo(u.x); Hs[r][hc + 1] = bfhi(u.x);
            Hs[r][hc + 2] = bflo(u.y); Hs[r][hc + 3] = bfhi(u.y);
        }
        for (int i = t; i < 64 * 40; i += 256) {
            int r = i / 40, c = i - r * 40;
            Ws[r][c] = W[(size_t)(k0 + r) * 40 + c];
        }
        __syncthreads();
        #pragma unroll 4
        for (int kk = 0; kk < 64; ++kk) {
            float a = Hs[tr][kk];
            float b[20];
            #pragma unroll
            for (int q = 0; q < 5; q++)
                *reinterpret_cast<float4*>(&b[q * 4]) =
                    *reinterpret_cast<float4*>(&Ws[kk][tg * 20 + q * 4]);
            #pragma unroll
            for (int j = 0; j < 20; j++) acc[j] = fmaf(a, b[j], acc[j]);
        }
        __syncthreads();
    }
    int gr = row0 + tr;
    if (gr < M) {
        #pragma unroll
        for (int q = 0; q < 5; q++) {
            float4 v = make_float4(acc[q * 4], acc[q * 4 + 1], acc[q * 4 + 2], acc[q * 4 + 3]);
            *reinterpret_cast<float4*>(C + (size_t)gr * 40 + tg * 20 + q * 4) = v;
        }
    }
}

// ---------------- aggregation (bf16): weight = dinv[s], final scale dinv[node] ----------------
__global__ __launch_bounds__(256) void aggb_kernel(const unsigned short* __restrict__ T,
        const int* __restrict__ row_ptr, const int* __restrict__ csr_src,
        const float* __restrict__ dinv, const float* __restrict__ bias,
        unsigned short* __restrict__ H, int n, int do_relu) {
    int wid = threadIdx.x >> 6, lane = threadIdx.x & 63;
    int node = blockIdx.x * 4 + wid;
    if (node >= n) return;
    int e0 = row_ptr[node], end = row_ptr[node + 1];
    float dn = dinv[node];
    float a0 = 0.f, a1 = 0.f, a2 = 0.f, a3 = 0.f;
    for (int base = e0; base < end; base += 64) {
        int cnt = min(64, end - base);
        int sv = 0; float wv = 0.f;
        if (lane < cnt) { sv = csr_src[base + lane]; wv = dinv[sv]; }
        int j = 0;
        for (; j + 3 < cnt; j += 4) {
            int s0 = __shfl(sv, j),     s1 = __shfl(sv, j + 1);
            int s2 = __shfl(sv, j + 2), s3 = __shfl(sv, j + 3);
            float w0 = __shfl(wv, j),     w1 = __shfl(wv, j + 1);
            float w2 = __shfl(wv, j + 2), w3 = __shfl(wv, j + 3);
            uint2 u0 = *reinterpret_cast<const uint2*>(T + (size_t)s0 * 256 + lane * 4);
            uint2 u1 = *reinterpret_cast<const uint2*>(T + (size_t)s1 * 256 + lane * 4);
            uint2 u2 = *reinterpret_cast<const uint2*>(T + (size_t)s2 * 256 + lane * 4);
            uint2 u3 = *reinterpret_cast<const uint2*>(T + (size_t)s3 * 256 + lane * 4);
            a0 = fmaf(w0, bflo(u0.x), a0); a1 = fmaf(w0, bfhi(u0.x), a1);
            a2 = fmaf(w0, bflo(u0.y), a2); a3 = fmaf(w0, bfhi(u0.y), a3);
            a0 = fmaf(w1, bflo(u1.x), a0); a1 = fmaf(w1, bfhi(u1.x), a1);
            a2 = fmaf(w1, bflo(u1.y), a2); a3 = fmaf(w1, bfhi(u1.y), a3);
            a0 = fmaf(w2, bflo(u2.x), a0); a1 = fmaf(w2, bfhi(u2.x), a1);
            a2 = fmaf(w2, bflo(u2.y), a2); a3 = fmaf(w2, bfhi(u2.y), a3);
            a0 = fmaf(w3, bflo(u3.x), a0); a1 = fmaf(w3, bfhi(u3.x), a1);
            a2 = fmaf(w3, bflo(u3.y), a2); a3 = fmaf(w3, bfhi(u3.y), a3);
        }
        for (; j < cnt; ++j) {
            int s0 = __shfl(sv, j);
            float w0 = __shfl(wv, j);
            uint2 u0 = *reinterpret_cast<const uint2*>(T + (size_t)s0 * 256 + lane * 4);
            a0 = fmaf(w0, bflo(u0.x), a0); a1 = fmaf(w0, bfhi(u0.x), a1);
            a2 = fmaf(w0, bflo(u0.y), a2); a3 = fmaf(w0, bfhi(u0.y), a3);
        }
    }
    float4 bb = reinterpret_cast<const float4*>(bias)[lane];
    a0 = fmaf(a0, dn, bb.x); a1 = fmaf(a1, dn, bb.y);
    a2 = fmaf(a2, dn, bb.z); a3 = fmaf(a3, dn, bb.w);
    if (do_relu) {
        a0 = fmaxf(a0, 0.f); a1 = fmaxf(a1, 0.f);
        a2 = fmaxf(a2, 0.f); a3 = fmaxf(a3, 0.f);
    }
    uint2 o;
    o.x = f2bf(a0) | ((unsigned)f2bf(a1) << 16);
    o.y = f2bf(a2) | ((unsigned)f2bf(a3) << 16);
    *reinterpret_cast<uint2*>(H + (size_t)node * 256 + lane * 4) = o;
}

// final layer: 40-ch aggregation + bias + log_softmax
__global__ __launch_bounds__(256) void agg40_kernel(const float* __restrict__ T3,
        const int* __restrict__ row_ptr, const int* __restrict__ csr_src,
        const float* __restrict__ dinv, const float* __restrict__ bias,
        float* __restrict__ Out, int n) {
    int wid = threadIdx.x >> 6, lane = threadIdx.x & 63;
    int node = blockIdx.x * 4 + wid;
    if (node >= n) return;
    bool act = lane < OC;
    int e0 = row_ptr[node], end = row_ptr[node + 1];
    float dn = dinv[node];
    float acc = 0.f;
    for (int base = e0; base < end; base += 64) {
        int cnt = min(64, end - base);
        int sv = 0; float wv = 0.f;
        if (lane < cnt) { sv = csr_src[base + lane]; wv = dinv[sv]; }
        int j = 0;
        for (; j + 3 < cnt; j += 4) {
            int s0 = __shfl(sv, j),     s1 = __shfl(sv, j + 1);
            int s2 = __shfl(sv, j + 2), s3 = __shfl(sv, j + 3);
            float w0 = __shfl(wv, j),     w1 = __shfl(wv, j + 1);
            float w2 = __shfl(wv, j + 2), w3 = __shfl(wv, j + 3);
            float v0 = act ? T3[(size_t)s0 * OC + lane] : 0.f;
            float v1 = act ? T3[(size_t)s1 * OC + lane] : 0.f;
            float v2 = act ? T3[(size_t)s2 * OC + lane] : 0.f;
            float v3 = act ? T3[(size_t)s3 * OC + lane] : 0.f;
            acc = fmaf(w0, v0, acc);
            acc = fmaf(w1, v1, acc);
            acc = fmaf(w2, v2, acc);
            acc = fmaf(w3, v3, acc);
        }
        for (; j < cnt; ++j) {
            int s0 = __shfl(sv, j);
            float w0 = __shfl(wv, j);
            float v0 = act ? T3[(size_t)s0 * OC + lane] : 0.f;
            acc = fmaf(w0, v0, acc);
        }
    }
    float bb = act ? bias[lane] : 0.f;
    float x = act ? (acc * dn + bb) : -INFINITY;
    float m = x;
    #pragma unroll
    for (int off = 32; off; off >>= 1) m = fmaxf(m, __shfl_xor(m, off));
    float ex = act ? expf(x - m) : 0.f;
    float ssum = ex;
    #pragma unroll
    for (int off = 32; off; off >>= 1) ssum += __shfl_xor(ssum, off);
    if (act) Out[(size_t)node * OC + lane] = x - m - logf(ssum);
}

// ---------------- launch ----------------

extern "C" void kernel_launch(void* const* d_in, const int* in_sizes, int n_in,
                              void* d_out, int out_size, void* d_ws, size_t ws_size,
                              hipStream_t stream) {
    const float* x  = (const float*)d_in[0];
    const int* ei   = (const int*)d_in[1];
    const int* esrc = ei;
    const int* edst = ei + NE;
    const float* W1 = (const float*)d_in[2];
    const float* b1 = (const float*)d_in[3];
    const float* W2 = (const float*)d_in[4];
    const float* b2 = (const float*)d_in[5];
    const float* W3 = (const float*)d_in[6];
    const float* b3 = (const float*)d_in[7];
    float* out = (float*)d_out;

    char* p = (char*)d_ws;
    int* deg      = (int*)p;   p += 400000;
    int* cursor   = (int*)p;   p += 400000;
    int* row_ptr  = (int*)p;   p += 400128;
    float* dinv   = (float*)p; p += 400000;
    int* bsum     = (int*)p;   p += 2048;
    int* boff     = (int*)p;   p += 2048;
    int* csr_src  = (int*)p;   p += (size_t)(NE + NN) * 4;
    unsigned short* Wt1 = (unsigned short*)p; p += 256 * 256 * 2;
    unsigned short* Wt2 = (unsigned short*)p; p += 256 * 256 * 2;
    unsigned short* Tb  = (unsigned short*)p; p += (size_t)NN * CH * 2;
    unsigned short* Hb  = (unsigned short*)p; p += (size_t)NN * CH * 2;
    float* T3     = (float*)p; p += (size_t)NN * OC * 4;

    hipMemsetAsync(deg, 0, 400000, stream);

    const int nb = (NN + 255) / 256;  // 391

    hist_kernel<<<2048, 256, 0, stream>>>(edst, deg, NE);
    dinv_kernel<<<nb, 256, 0, stream>>>(deg, dinv, NN);
    scan1_kernel<<<nb, 256, 0, stream>>>(deg, row_ptr, bsum, NN);
    scan2_kernel<<<1, 512, 0, stream>>>(bsum, boff, row_ptr, nb, NN);
    scan3_kernel<<<nb, 256, 0, stream>>>(row_ptr, boff, NN);
    cpy_kernel<<<nb, 256, 0, stream>>>(row_ptr, cursor, NN);
    fill_kernel<<<2048, 256, 0, stream>>>(esrc, edst, row_ptr, cursor, csr_src, NE, NN);

    {
        dim3 g(16, 16), b(16, 16);
        wtrans_kernel<<<g, b, 0, stream>>>(W1, Wt1);
        wtrans_kernel<<<g, b, 0, stream>>>(W2, Wt2);
    }

    dim3 gg((NN + 127) / 128, 2);
    gemm_l1_kernel<<<gg, 256, 0, stream>>>(x, Wt1, Tb, NN);
    aggb_kernel<<<NN / 4, 256, 0, stream>>>(Tb, row_ptr, csr_src, dinv, b1, Hb, NN, 1);
    gemm_bf16_kernel<<<gg, 256, 0, stream>>>(Hb, Wt2, Tb, NN);
    aggb_kernel<<<NN / 4, 256, 0, stream>>>(Tb, row_ptr, csr_src, dinv, b2, Hb, NN, 1);
    gemm40_kernel<<<(NN + 127) / 128, 256, 0, stream>>>(Hb, W3, T3, NN);
    agg40_kernel<<<NN / 4, 256, 0, stream>>>(T3, row_ptr, csr_src, dinv, b3, out, NN);
}

// Round 7
// 741.084 us; speedup vs baseline: 1.1659x; 1.1659x over previous
//
#include <hip/hip_runtime.h>
#include <math.h>
#include <cstddef>

#define NN 100000
#define NE 1600000
#define CH 256
#define OC 40

#define NBKT 128
#define BKN  782          // nodes per bucket; 128*782 = 100096 >= NN
#define ACH  4096         // edges per passA block
#define CAPB 14848        // passB2 LDS slots (mean span 13294, sigma ~111)

typedef __attribute__((ext_vector_type(8))) short bf16x8;
typedef __attribute__((ext_vector_type(4))) float f32x4;

static __device__ __forceinline__ unsigned short f2bf(float f) {
    unsigned int u = __float_as_uint(f);
    unsigned int r = (u + 0x7FFFu + ((u >> 16) & 1u)) >> 16;
    return (unsigned short)r;
}
static __device__ __forceinline__ float bflo(unsigned int u) {
    return __uint_as_float(u << 16);
}
static __device__ __forceinline__ float bfhi(unsigned int u) {
    return __uint_as_float(u & 0xFFFF0000u);
}
static __device__ __forceinline__ uint4 ld_f32x8_to_bf8(const float* p) {
    float4 a = *reinterpret_cast<const float4*>(p);
    float4 b = *reinterpret_cast<const float4*>(p + 4);
    uint4 r;
    r.x = f2bf(a.x) | ((unsigned)f2bf(a.y) << 16);
    r.y = f2bf(a.z) | ((unsigned)f2bf(a.w) << 16);
    r.z = f2bf(b.x) | ((unsigned)f2bf(b.y) << 16);
    r.w = f2bf(b.z) | ((unsigned)f2bf(b.w) << 16);
    return r;
}

// ---------------- graph build: bucketed counting sort ----------------

// 128-bucket histogram of dst/BKN
__global__ __launch_bounds__(256) void bhist_kernel(const int* __restrict__ dst,
        int* __restrict__ gh, int E) {
    __shared__ int h[NBKT];
    int t = threadIdx.x;
    if (t < NBKT) h[t] = 0;
    __syncthreads();
    int i0 = blockIdx.x * ACH;
    for (int i = i0 + t; i < i0 + ACH && i < E; i += 256)
        atomicAdd(&h[(unsigned)dst[i] / BKN], 1);
    __syncthreads();
    if (t < NBKT && h[t]) atomicAdd(&gh[t], h[t]);
}

// exclusive scan of gh -> bbase; gcur = bbase
__global__ __launch_bounds__(128) void bscan_kernel(const int* __restrict__ gh,
        int* __restrict__ bbase, int* __restrict__ gcur) {
    __shared__ int s[NBKT];
    int t = threadIdx.x;
    int v = gh[t];
    s[t] = v;
    __syncthreads();
    #pragma unroll
    for (int off = 1; off < NBKT; off <<= 1) {
        int u = (t >= off) ? s[t - off] : 0;
        __syncthreads();
        s[t] += u;
        __syncthreads();
    }
    int e = s[t] - v;
    bbase[t] = e;
    gcur[t] = e;
}

// bin (src,dst) pairs into bucket-contiguous staging, coalesced writes
__global__ __launch_bounds__(256) void passA_kernel(const int* __restrict__ src,
        const int* __restrict__ dst, int* __restrict__ gcur,
        int2* __restrict__ stag, int E) {
    __shared__ int2 pairs[ACH];
    __shared__ unsigned char pbkt[ACH];
    __shared__ int h[NBKT], lofs[NBKT], gofs[NBKT];
    int t = threadIdx.x;
    if (t < NBKT) h[t] = 0;
    __syncthreads();

    int i0 = blockIdx.x * ACH;
    int cnt = min(ACH, E - i0);

    int myb[ACH / 256], myr[ACH / 256], mys[ACH / 256], myd[ACH / 256];
    int k = 0;
    for (int i = t; i < cnt; i += 256, ++k) {
        int s = src[i0 + i], d = dst[i0 + i];
        int b = (unsigned)d / BKN;
        mys[k] = s; myd[k] = d; myb[k] = b;
        myr[k] = atomicAdd(&h[b], 1);
    }
    __syncthreads();
    // exclusive scan h -> lofs
    {
        __shared__ int sc[NBKT];
        if (t < NBKT) sc[t] = h[t];
        __syncthreads();
        #pragma unroll
        for (int off = 1; off < NBKT; off <<= 1) {
            int u = (t >= off && t < NBKT) ? sc[t - off] : 0;
            __syncthreads();
            if (t < NBKT) sc[t] += u;
            __syncthreads();
        }
        if (t < NBKT) lofs[t] = sc[t] - h[t];
    }
    __syncthreads();
    // place into LDS
    k = 0;
    for (int i = t; i < cnt; i += 256, ++k) {
        int p = lofs[myb[k]] + myr[k];
        pairs[p] = make_int2(mys[k], myd[k]);
        pbkt[p] = (unsigned char)myb[k];
    }
    // claim global space per bucket
    if (t < NBKT && h[t]) gofs[t] = atomicAdd(&gcur[t], h[t]);
    __syncthreads();
    // stream out: sequential within each bucket run
    for (int j = t; j < cnt; j += 256) {
        int b = pbkt[j];
        stag[gofs[b] + (j - lofs[b])] = pairs[j];
    }
}

// per-bucket degree histogram -> deg (coalesced write)
__global__ __launch_bounds__(256) void passB1_kernel(const int2* __restrict__ stag,
        const int* __restrict__ bbase, const int* __restrict__ gh,
        int* __restrict__ deg, int n) {
    __shared__ int lh[BKN];
    int b = blockIdx.x;
    int t = threadIdx.x;
    int node0 = b * BKN;
    int nn = min(BKN, n - node0);
    if (nn <= 0) return;
    for (int i = t; i < nn; i += 256) lh[i] = 0;
    __syncthreads();
    int e0 = bbase[b], cnt = gh[b];
    for (int i = t; i < cnt; i += 256)
        atomicAdd(&lh[stag[e0 + i].y - node0], 1);
    __syncthreads();
    for (int i = t; i < nn; i += 256) deg[node0 + i] = lh[i];
}

__global__ void dinv_kernel(const int* __restrict__ deg, float* __restrict__ dinv, int n) {
    int i = blockIdx.x * blockDim.x + threadIdx.x;
    if (i < n) dinv[i] = rsqrtf((float)deg[i] + 1.0f);
}

// ---- hierarchical scan: row_ptr = exclusive_scan(deg+1), row_ptr[n] = total ----
__global__ __launch_bounds__(256) void scan1_kernel(const int* __restrict__ deg,
        int* __restrict__ row_ptr, int* __restrict__ bsum, int n) {
    __shared__ int s[256];
    int t = threadIdx.x;
    int i = blockIdx.x * 256 + t;
    int v = (i < n) ? deg[i] + 1 : 0;
    s[t] = v;
    __syncthreads();
    #pragma unroll
    for (int off = 1; off < 256; off <<= 1) {
        int u = (t >= off) ? s[t - off] : 0;
        __syncthreads();
        s[t] += u;
        __syncthreads();
    }
    if (i < n) row_ptr[i] = s[t] - v;
    if (t == 255) bsum[blockIdx.x] = s[255];
}

__global__ __launch_bounds__(512) void scan2_kernel(const int* __restrict__ bsum,
        int* __restrict__ boff, int* __restrict__ row_ptr, int nb, int n) {
    __shared__ int s[512];
    int t = threadIdx.x;
    int v = (t < nb) ? bsum[t] : 0;
    s[t] = v;
    __syncthreads();
    #pragma unroll
    for (int off = 1; off < 512; off <<= 1) {
        int u = (t >= off) ? s[t - off] : 0;
        __syncthreads();
        s[t] += u;
        __syncthreads();
    }
    if (t < nb) boff[t] = s[t] - v;
    if (t == nb - 1) row_ptr[n] = s[t];
}

__global__ __launch_bounds__(256) void scan3_kernel(int* __restrict__ row_ptr,
        const int* __restrict__ boff, int n) {
    int i = blockIdx.x * 256 + threadIdx.x;
    if (i < n) row_ptr[i] += boff[i >> 8];
}

// per-bucket counting scatter into LDS CSR image, coalesced stream-out
__global__ __launch_bounds__(256) void passB2_kernel(const int2* __restrict__ stag,
        const int* __restrict__ bbase, const int* __restrict__ gh,
        const int* __restrict__ row_ptr, int* __restrict__ csr_src, int n) {
    __shared__ int lds_out[CAPB];
    __shared__ int lds_cur[BKN];
    int b = blockIdx.x;
    int t = threadIdx.x;
    int node0 = b * BKN;
    int nn = min(BKN, n - node0);
    if (nn <= 0) return;
    int base = row_ptr[node0];
    int span = row_ptr[node0 + nn] - base;
    for (int i = t; i < nn; i += 256) lds_cur[i] = row_ptr[node0 + i] - base;
    __syncthreads();
    int e0 = bbase[b], cnt = gh[b];
    for (int i = t; i < cnt; i += 256) {
        int2 pr = stag[e0 + i];
        int p = atomicAdd(&lds_cur[pr.y - node0], 1);
        if (p < CAPB) lds_out[p] = pr.x;
        else csr_src[base + p] = pr.x;          // statistical overflow fallback
    }
    // self-loops: last slot of each row
    for (int i = t; i < nn; i += 256) {
        int v = node0 + i;
        int p = row_ptr[v + 1] - 1 - base;
        if (p < CAPB) lds_out[p] = v;
        else csr_src[base + p] = v;
    }
    __syncthreads();
    int lim = min(span, CAPB);
    for (int j = t; j < lim; j += 256) csr_src[base + j] = lds_out[j];
}

// ---------------- prep ----------------

__global__ void wtrans_kernel(const float* __restrict__ W, unsigned short* __restrict__ Wt) {
    __shared__ float tile[16][17];
    int k = blockIdx.y * 16 + threadIdx.y;
    int n = blockIdx.x * 16 + threadIdx.x;
    tile[threadIdx.y][threadIdx.x] = W[(size_t)k * 256 + n];
    __syncthreads();
    int on = blockIdx.x * 16 + threadIdx.y;
    int ok = blockIdx.y * 16 + threadIdx.x;
    Wt[(size_t)on * 256 + ok] = f2bf(tile[threadIdx.x][threadIdx.y]);
}

// ---------------- layer-1 GEMM: C[M x 256] = bf16(A_f32) @ Wt^T ----------------
__global__ __launch_bounds__(256) void gemm_l1_kernel(
        const float* __restrict__ A, const unsigned short* __restrict__ Wt,
        unsigned short* __restrict__ C, int M) {
    __shared__ __align__(16) unsigned short As[128 * 40];
    __shared__ __align__(16) unsigned short Bs[128 * 40];
    const int t = threadIdx.x;
    const int l = t & 63;
    const int w = t >> 6;
    const int wr = w >> 1, wc = w & 1;
    const int row0 = blockIdx.x * 128;
    const int col0 = blockIdx.y * 128;

    f32x4 acc[4][4];
    #pragma unroll
    for (int m = 0; m < 4; m++)
        #pragma unroll
        for (int n = 0; n < 4; n++) acc[m][n] = (f32x4){0.f, 0.f, 0.f, 0.f};

    const int sr = t >> 2;
    const int sc = (t & 3) * 8;
    const int rl = l & 15;
    const int kb = (l >> 4) * 8;

    uint4 va[2], ub[2];
    #pragma unroll
    for (int p = 0; p < 2; p++) {
        int r = sr + p * 64;
        int gr = row0 + r;
        va[p] = (gr < M) ? ld_f32x8_to_bf8(A + (size_t)gr * 256 + sc)
                         : make_uint4(0u, 0u, 0u, 0u);
        ub[p] = *reinterpret_cast<const uint4*>(Wt + (size_t)(col0 + r) * 256 + sc);
    }

    for (int k0 = 0; k0 < 256; k0 += 32) {
        #pragma unroll
        for (int p = 0; p < 2; p++) {
            int r = sr + p * 64;
            *reinterpret_cast<uint4*>(&As[r * 40 + sc]) = va[p];
            *reinterpret_cast<uint4*>(&Bs[r * 40 + sc]) = ub[p];
        }
        __syncthreads();
        if (k0 + 32 < 256) {
            #pragma unroll
            for (int p = 0; p < 2; p++) {
                int r = sr + p * 64;
                int gr = row0 + r;
                va[p] = (gr < M) ? ld_f32x8_to_bf8(A + (size_t)gr * 256 + k0 + 32 + sc)
                                 : make_uint4(0u, 0u, 0u, 0u);
                ub[p] = *reinterpret_cast<const uint4*>(Wt + (size_t)(col0 + r) * 256 + k0 + 32 + sc);
            }
        }
        bf16x8 af[4], bfr[4];
        #pragma unroll
        for (int m = 0; m < 4; m++)
            af[m] = *reinterpret_cast<const bf16x8*>(&As[(wr * 64 + m * 16 + rl) * 40 + kb]);
        #pragma unroll
        for (int n = 0; n < 4; n++)
            bfr[n] = *reinterpret_cast<const bf16x8*>(&Bs[(wc * 64 + n * 16 + rl) * 40 + kb]);
        #pragma unroll
        for (int m = 0; m < 4; m++)
            #pragma unroll
            for (int n = 0; n < 4; n++)
                acc[m][n] = __builtin_amdgcn_mfma_f32_16x16x32_bf16(af[m], bfr[n], acc[m][n], 0, 0, 0);
        __syncthreads();
    }
    const int rh = l >> 4;
    #pragma unroll
    for (int m = 0; m < 4; m++) {
        #pragma unroll
        for (int n = 0; n < 4; n++) {
            #pragma unroll
            for (int j = 0; j < 4; j++) {
                int gr = row0 + wr * 64 + m * 16 + rh * 4 + j;
                int gc = col0 + wc * 64 + n * 16 + rl;
                if (gr < M) C[(size_t)gr * 256 + gc] = f2bf(acc[m][n][j]);
            }
        }
    }
}

// ---------------- bf16 MFMA GEMM (bf16 A) ----------------
__global__ __launch_bounds__(256) void gemm_bf16_kernel(
        const unsigned short* __restrict__ A, const unsigned short* __restrict__ Wt,
        unsigned short* __restrict__ C, int M) {
    __shared__ __align__(16) unsigned short As[128 * 40];
    __shared__ __align__(16) unsigned short Bs[128 * 40];
    const int t = threadIdx.x;
    const int l = t & 63;
    const int w = t >> 6;
    const int wr = w >> 1, wc = w & 1;
    const int row0 = blockIdx.x * 128;
    const int col0 = blockIdx.y * 128;

    f32x4 acc[4][4];
    #pragma unroll
    for (int m = 0; m < 4; m++)
        #pragma unroll
        for (int n = 0; n < 4; n++) acc[m][n] = (f32x4){0.f, 0.f, 0.f, 0.f};

    const int sr = t >> 2;
    const int sc = (t & 3) * 8;
    const int rl = l & 15;
    const int kb = (l >> 4) * 8;

    uint4 va[2], ub[2];
    #pragma unroll
    for (int p = 0; p < 2; p++) {
        int r = sr + p * 64;
        int gr = row0 + r;
        va[p] = (gr < M) ? *reinterpret_cast<const uint4*>(A + (size_t)gr * 256 + sc)
                         : make_uint4(0u, 0u, 0u, 0u);
        ub[p] = *reinterpret_cast<const uint4*>(Wt + (size_t)(col0 + r) * 256 + sc);
    }

    for (int k0 = 0; k0 < 256; k0 += 32) {
        #pragma unroll
        for (int p = 0; p < 2; p++) {
            int r = sr + p * 64;
            *reinterpret_cast<uint4*>(&As[r * 40 + sc]) = va[p];
            *reinterpret_cast<uint4*>(&Bs[r * 40 + sc]) = ub[p];
        }
        __syncthreads();
        if (k0 + 32 < 256) {
            #pragma unroll
            for (int p = 0; p < 2; p++) {
                int r = sr + p * 64;
                int gr = row0 + r;
                va[p] = (gr < M) ? *reinterpret_cast<const uint4*>(A + (size_t)gr * 256 + k0 + 32 + sc)
                                 : make_uint4(0u, 0u, 0u, 0u);
                ub[p] = *reinterpret_cast<const uint4*>(Wt + (size_t)(col0 + r) * 256 + k0 + 32 + sc);
            }
        }
        bf16x8 af[4], bfr[4];
        #pragma unroll
        for (int m = 0; m < 4; m++)
            af[m] = *reinterpret_cast<const bf16x8*>(&As[(wr * 64 + m * 16 + rl) * 40 + kb]);
        #pragma unroll
        for (int n = 0; n < 4; n++)
            bfr[n] = *reinterpret_cast<const bf16x8*>(&Bs[(wc * 64 + n * 16 + rl) * 40 + kb]);
        #pragma unroll
        for (int m = 0; m < 4; m++)
            #pragma unroll
            for (int n = 0; n < 4; n++)
                acc[m][n] = __builtin_amdgcn_mfma_f32_16x16x32_bf16(af[m], bfr[n], acc[m][n], 0, 0, 0);
        __syncthreads();
    }
    const int rh = l >> 4;
    #pragma unroll
    for (int m = 0; m < 4; m++) {
        #pragma unroll
        for (int n = 0; n < 4; n++) {
            #pragma unroll
            for (int j = 0; j < 4; j++) {
                int gr = row0 + wr * 64 + m * 16 + rh * 4 + j;
                int gc = col0 + wc * 64 + n * 16 + rl;
                if (gr < M) C[(size_t)gr * 256 + gc] = f2bf(acc[m][n][j]);
            }
        }
    }
}

// ---------------- GEMM: T3[M x 40] = Hb(bf16) @ W3(f32) ----------------
__global__ __launch_bounds__(256) void gemm40_kernel(const unsigned short* __restrict__ A,
                                                     const float* __restrict__ W,
                                                     float* __restrict__ C, int M) {
    __shared__ float Hs[128][65];
    __shared__ float Ws[64][40];
    const int t = threadIdx.x;
    const int tr = t & 127;
    const int tg = t >> 7;
    const int row0 = blockIdx.x * 128;
    float acc[20];
    #pragma unroll
    for (int j = 0; j < 20; j++) acc[j] = 0.f;

    const int hr = t >> 4;
    const int hc = (t & 15) << 2;

    for (int k0 = 0; k0 < 256; k0 += 64) {
        #pragma unroll
        for (int p = 0; p < 8; p++) {
            int r = hr + p * 16;
            int gr = row0 + r;
            uint2 u = make_uint2(0u, 0u);
            if (gr < M) u = *reinterpret_cast<const uint2*>(A + (size_t)gr * 256 + k0 + hc);
            Hs[r][hc] = bflo(u.x); Hs[r][hc + 1] = bfhi(u.x);
            Hs[r][hc + 2] = bflo(u.y); Hs[r][hc + 3] = bfhi(u.y);
        }
        for (int i = t; i < 64 * 40; i += 256) {
            int r = i / 40, c = i - r * 40;
            Ws[r][c] = W[(size_t)(k0 + r) * 40 + c];
        }
        __syncthreads();
        #pragma unroll 4
        for (int kk = 0; kk < 64; ++kk) {
            float a = Hs[tr][kk];
            float b[20];
            #pragma unroll
            for (int q = 0; q < 5; q++)
                *reinterpret_cast<float4*>(&b[q * 4]) =
                    *reinterpret_cast<float4*>(&Ws[kk][tg * 20 + q * 4]);
            #pragma unroll
            for (int j = 0; j < 20; j++) acc[j] = fmaf(a, b[j], acc[j]);
        }
        __syncthreads();
    }
    int gr = row0 + tr;
    if (gr < M) {
        #pragma unroll
        for (int q = 0; q < 5; q++) {
            float4 v = make_float4(acc[q * 4], acc[q * 4 + 1], acc[q * 4 + 2], acc[q * 4 + 3]);
            *reinterpret_cast<float4*>(C + (size_t)gr * 40 + tg * 20 + q * 4) = v;
        }
    }
}

// ---------------- aggregation (bf16): weight = dinv[s], final scale dinv[node] ----------------
__global__ __launch_bounds__(256) void aggb_kernel(const unsigned short* __restrict__ T,
        const int* __restrict__ row_ptr, const int* __restrict__ csr_src,
        const float* __restrict__ dinv, const float* __restrict__ bias,
        unsigned short* __restrict__ H, int n, int do_relu) {
    int wid = threadIdx.x >> 6, lane = threadIdx.x & 63;
    int node = blockIdx.x * 4 + wid;
    if (node >= n) return;
    int e0 = row_ptr[node], end = row_ptr[node + 1];
    float dn = dinv[node];
    float a0 = 0.f, a1 = 0.f, a2 = 0.f, a3 = 0.f;
    for (int base = e0; base < end; base += 64) {
        int cnt = min(64, end - base);
        int sv = 0; float wv = 0.f;
        if (lane < cnt) { sv = csr_src[base + lane]; wv = dinv[sv]; }
        int j = 0;
        for (; j + 3 < cnt; j += 4) {
            int s0 = __shfl(sv, j),     s1 = __shfl(sv, j + 1);
            int s2 = __shfl(sv, j + 2), s3 = __shfl(sv, j + 3);
            float w0 = __shfl(wv, j),     w1 = __shfl(wv, j + 1);
            float w2 = __shfl(wv, j + 2), w3 = __shfl(wv, j + 3);
            uint2 u0 = *reinterpret_cast<const uint2*>(T + (size_t)s0 * 256 + lane * 4);
            uint2 u1 = *reinterpret_cast<const uint2*>(T + (size_t)s1 * 256 + lane * 4);
            uint2 u2 = *reinterpret_cast<const uint2*>(T + (size_t)s2 * 256 + lane * 4);
            uint2 u3 = *reinterpret_cast<const uint2*>(T + (size_t)s3 * 256 + lane * 4);
            a0 = fmaf(w0, bflo(u0.x), a0); a1 = fmaf(w0, bfhi(u0.x), a1);
            a2 = fmaf(w0, bflo(u0.y), a2); a3 = fmaf(w0, bfhi(u0.y), a3);
            a0 = fmaf(w1, bflo(u1.x), a0); a1 = fmaf(w1, bfhi(u1.x), a1);
            a2 = fmaf(w1, bflo(u1.y), a2); a3 = fmaf(w1, bfhi(u1.y), a3);
            a0 = fmaf(w2, bflo(u2.x), a0); a1 = fmaf(w2, bfhi(u2.x), a1);
            a2 = fmaf(w2, bflo(u2.y), a2); a3 = fmaf(w2, bfhi(u2.y), a3);
            a0 = fmaf(w3, bflo(u3.x), a0); a1 = fmaf(w3, bfhi(u3.x), a1);
            a2 = fmaf(w3, bflo(u3.y), a2); a3 = fmaf(w3, bfhi(u3.y), a3);
        }
        for (; j < cnt; ++j) {
            int s0 = __shfl(sv, j);
            float w0 = __shfl(wv, j);
            uint2 u0 = *reinterpret_cast<const uint2*>(T + (size_t)s0 * 256 + lane * 4);
            a0 = fmaf(w0, bflo(u0.x), a0); a1 = fmaf(w0, bfhi(u0.x), a1);
            a2 = fmaf(w0, bflo(u0.y), a2); a3 = fmaf(w0, bfhi(u0.y), a3);
        }
    }
    float4 bb = reinterpret_cast<const float4*>(bias)[lane];
    a0 = fmaf(a0, dn, bb.x); a1 = fmaf(a1, dn, bb.y);
    a2 = fmaf(a2, dn, bb.z); a3 = fmaf(a3, dn, bb.w);
    if (do_relu) {
        a0 = fmaxf(a0, 0.f); a1 = fmaxf(a1, 0.f);
        a2 = fmaxf(a2, 0.f); a3 = fmaxf(a3, 0.f);
    }
    uint2 o;
    o.x = f2bf(a0) | ((unsigned)f2bf(a1) << 16);
    o.y = f2bf(a2) | ((unsigned)f2bf(a3) << 16);
    *reinterpret_cast<uint2*>(H + (size_t)node * 256 + lane * 4) = o;
}

// final layer: 40-ch aggregation + bias + log_softmax
__global__ __launch_bounds__(256) void agg40_kernel(const float* __restrict__ T3,
        const int* __restrict__ row_ptr, const int* __restrict__ csr_src,
        const float* __restrict__ dinv, const float* __restrict__ bias,
        float* __restrict__ Out, int n) {
    int wid = threadIdx.x >> 6, lane = threadIdx.x & 63;
    int node = blockIdx.x * 4 + wid;
    if (node >= n) return;
    bool act = lane < OC;
    int e0 = row_ptr[node], end = row_ptr[node + 1];
    float dn = dinv[node];
    float acc = 0.f;
    for (int base = e0; base < end; base += 64) {
        int cnt = min(64, end - base);
        int sv = 0; float wv = 0.f;
        if (lane < cnt) { sv = csr_src[base + lane]; wv = dinv[sv]; }
        int j = 0;
        for (; j + 3 < cnt; j += 4) {
            int s0 = __shfl(sv, j),     s1 = __shfl(sv, j + 1);
            int s2 = __shfl(sv, j + 2), s3 = __shfl(sv, j + 3);
            float w0 = __shfl(wv, j),     w1 = __shfl(wv, j + 1);
            float w2 = __shfl(wv, j + 2), w3 = __shfl(wv, j + 3);
            float v0 = act ? T3[(size_t)s0 * OC + lane] : 0.f;
            float v1 = act ? T3[(size_t)s1 * OC + lane] : 0.f;
            float v2 = act ? T3[(size_t)s2 * OC + lane] : 0.f;
            float v3 = act ? T3[(size_t)s3 * OC + lane] : 0.f;
            acc = fmaf(w0, v0, acc);
            acc = fmaf(w1, v1, acc);
            acc = fmaf(w2, v2, acc);
            acc = fmaf(w3, v3, acc);
        }
        for (; j < cnt; ++j) {
            int s0 = __shfl(sv, j);
            float w0 = __shfl(wv, j);
            float v0 = act ? T3[(size_t)s0 * OC + lane] : 0.f;
            acc = fmaf(w0, v0, acc);
        }
    }
    float bb = act ? bias[lane] : 0.f;
    float x = act ? (acc * dn + bb) : -INFINITY;
    float m = x;
    #pragma unroll
    for (int off = 32; off; off >>= 1) m = fmaxf(m, __shfl_xor(m, off));
    float ex = act ? expf(x - m) : 0.f;
    float ssum = ex;
    #pragma unroll
    for (int off = 32; off; off >>= 1) ssum += __shfl_xor(ssum, off);
    if (act) Out[(size_t)node * OC + lane] = x - m - logf(ssum);
}

// ---------------- launch ----------------

extern "C" void kernel_launch(void* const* d_in, const int* in_sizes, int n_in,
                              void* d_out, int out_size, void* d_ws, size_t ws_size,
                              hipStream_t stream) {
    const float* x  = (const float*)d_in[0];
    const int* ei   = (const int*)d_in[1];
    const int* esrc = ei;
    const int* edst = ei + NE;
    const float* W1 = (const float*)d_in[2];
    const float* b1 = (const float*)d_in[3];
    const float* W2 = (const float*)d_in[4];
    const float* b2 = (const float*)d_in[5];
    const float* W3 = (const float*)d_in[6];
    const float* b3 = (const float*)d_in[7];
    float* out = (float*)d_out;

    char* p = (char*)d_ws;
    int* deg      = (int*)p;   p += 400000;
    int* row_ptr  = (int*)p;   p += 400128;
    float* dinv   = (float*)p; p += 400000;
    int* gh       = (int*)p;   p += 512;     // bucket hist
    int* bbase    = (int*)p;   p += 512;     // bucket base offsets
    int* gcur     = (int*)p;   p += 512;     // bucket cursors (passA)
    int* bsum     = (int*)p;   p += 2048;
    int* boff     = (int*)p;   p += 2048;
    int2* stag    = (int2*)p;  p += (size_t)NE * 8;   // bucketed (src,dst) staging
    int* csr_src  = (int*)p;   p += (size_t)(NE + NN) * 4;
    unsigned short* Wt1 = (unsigned short*)p; p += 256 * 256 * 2;
    unsigned short* Wt2 = (unsigned short*)p; p += 256 * 256 * 2;
    unsigned short* Tb  = (unsigned short*)p; p += (size_t)NN * CH * 2;
    unsigned short* Hb  = (unsigned short*)p; p += (size_t)NN * CH * 2;
    float* T3     = (float*)p; p += (size_t)NN * OC * 4;

    hipMemsetAsync(gh, 0, 512, stream);

    const int nb = (NN + 255) / 256;          // 391
    const int nba = (NE + ACH - 1) / ACH;     // 391

    bhist_kernel<<<nba, 256, 0, stream>>>(edst, gh, NE);
    bscan_kernel<<<1, NBKT, 0, stream>>>(gh, bbase, gcur);
    passA_kernel<<<nba, 256, 0, stream>>>(esrc, edst, gcur, stag, NE);
    passB1_kernel<<<NBKT, 256, 0, stream>>>(stag, bbase, gh, deg, NN);
    dinv_kernel<<<nb, 256, 0, stream>>>(deg, dinv, NN);
    scan1_kernel<<<nb, 256, 0, stream>>>(deg, row_ptr, bsum, NN);
    scan2_kernel<<<1, 512, 0, stream>>>(bsum, boff, row_ptr, nb, NN);
    scan3_kernel<<<nb, 256, 0, stream>>>(row_ptr, boff, NN);
    passB2_kernel<<<NBKT, 256, 0, stream>>>(stag, bbase, gh, row_ptr, csr_src, NN);

    {
        dim3 g(16, 16), b(16, 16);
        wtrans_kernel<<<g, b, 0, stream>>>(W1, Wt1);
        wtrans_kernel<<<g, b, 0, stream>>>(W2, Wt2);
    }

    dim3 gg((NN + 127) / 128, 2);
    gemm_l1_kernel<<<gg, 256, 0, stream>>>(x, Wt1, Tb, NN);
    aggb_kernel<<<NN / 4, 256, 0, stream>>>(Tb, row_ptr, csr_src, dinv, b1, Hb, NN, 1);
    gemm_bf16_kernel<<<gg, 256, 0, stream>>>(Hb, Wt2, Tb, NN);
    aggb_kernel<<<NN / 4, 256, 0, stream>>>(Tb, row_ptr, csr_src, dinv, b2, Hb, NN, 1);
    gemm40_kernel<<<(NN + 127) / 128, 256, 0, stream>>>(Hb, W3, T3, NN);
    agg40_kernel<<<NN / 4, 256, 0, stream>>>(T3, row_ptr, csr_src, dinv, b3, out, NN);
}